// Round 2
// baseline (671.094 us; speedup 1.0000x reference)
//
#include <hip/hip_runtime.h>

// SumPooling / segment_sum: out[s, d] = sum_{i: index[i]==s} x[i, d]
// x: (1e6, 128) fp32, index: (1e6,) sorted int32, out: (16384, 128) fp32.
//
// v3 strategy: one 64-lane wave per 128-row chunk.
//  - lanes 0-31 process even rows, lanes 32-63 odd rows: float4/lane
//    => 1 KiB per global_load instruction.
//  - the wave's 128 segment ids are pre-staged: lane l packs ids of rows
//    (2l, 2l+1) into ONE 32-bit word (ids < 16384 fit in 16 bits);
//    per pair a single __shfl broadcasts both halves' ids.
//  - 4 float4 loads in flight per wave (batched before the branchy phase).
//  - __launch_bounds__(256, 8) pins VGPR <= 64 so all ~30.5 waves/CU are
//    resident simultaneously (one dispatch round, max latency hiding).
//  - run-length accumulate per half-wave (index sorted); atomicAdd only at
//    segment boundaries / chunk edges.

constexpr int D_FEAT = 128;
constexpr int D4 = D_FEAT / 4;            // float4 elements per row = 32
constexpr int ROWS_PER_WAVE = 128;
constexpr int WAVES_PER_BLOCK = 4;        // block = 256 threads

__global__ void zero_out_kernel(float4* __restrict__ out, int n4) {
    int i = blockIdx.x * blockDim.x + threadIdx.x;
    int stride = gridDim.x * blockDim.x;
    for (; i < n4; i += stride) {
        out[i] = make_float4(0.f, 0.f, 0.f, 0.f);
    }
}

__device__ __forceinline__ void flush_acc(float* __restrict__ out, int seg,
                                          int cq, const float4& a) {
    float* o = out + (long)seg * D_FEAT + cq * 4;
    atomicAdd(o + 0, a.x);
    atomicAdd(o + 1, a.y);
    atomicAdd(o + 2, a.z);
    atomicAdd(o + 3, a.w);
}

__global__ __launch_bounds__(256, 8) void segsum_kernel(
        const float* __restrict__ x,
        const int* __restrict__ index,
        float* __restrict__ out,
        int n_rows) {
    const int lane = threadIdx.x & 63;
    const int half = lane >> 5;            // 0: even rows, 1: odd rows
    const int cq   = lane & 31;            // float4 column within the row
    const long wave = (long)blockIdx.x * WAVES_PER_BLOCK + (threadIdx.x >> 6);

    long row0 = wave * ROWS_PER_WAVE;
    if (row0 >= n_rows) return;
    long rend = row0 + ROWS_PER_WAVE;
    if (rend > n_rows) rend = n_rows;
    const int nr = (int)(rend - row0);
    const int npairs = nr >> 1;
    const int odd = nr & 1;

    // Stage this wave's 128 segment ids, packed 2-per-lane (16 bits each).
    int pack = 0;
    {
        long ib = row0 + 2 * lane;
        if (ib + 1 < (long)n_rows) {
            int2 t = *(const int2*)(index + ib);
            pack = (t.x & 0xFFFF) | (t.y << 16);
        } else if (ib < (long)n_rows) {
            pack = index[ib] & 0xFFFF;
        }
    }
    const int sh = half << 4;              // 0 or 16: which id this half uses

    int cur_seg = (__shfl(pack, 0) >> sh) & 0xFFFF;
    float4 acc = make_float4(0.f, 0.f, 0.f, 0.f);

    // This lane's float4 pointer in row (row0 + half); advances 2 rows/pair.
    const float4* __restrict__ xp =
        (const float4*)x + (row0 + half) * (long)D4 + cq;

    int p = 0;
    constexpr int U = 4;  // pairs per batch => 8 rows, 4 loads in flight
    for (; p + U <= npairs; p += U, xp += 2 * U * D4) {
        // Issue all loads first: one base address + imm offsets 0/1/2/3 KiB.
        float4 v0 = xp[0 * 2 * D4];
        float4 v1 = xp[1 * 2 * D4];
        float4 v2 = xp[2 * 2 * D4];
        float4 v3 = xp[3 * 2 * D4];

        int s0 = (__shfl(pack, p + 0) >> sh) & 0xFFFF;
        if (s0 != cur_seg) { flush_acc(out, cur_seg, cq, acc); cur_seg = s0; acc = v0; }
        else { acc.x += v0.x; acc.y += v0.y; acc.z += v0.z; acc.w += v0.w; }

        int s1 = (__shfl(pack, p + 1) >> sh) & 0xFFFF;
        if (s1 != cur_seg) { flush_acc(out, cur_seg, cq, acc); cur_seg = s1; acc = v1; }
        else { acc.x += v1.x; acc.y += v1.y; acc.z += v1.z; acc.w += v1.w; }

        int s2 = (__shfl(pack, p + 2) >> sh) & 0xFFFF;
        if (s2 != cur_seg) { flush_acc(out, cur_seg, cq, acc); cur_seg = s2; acc = v2; }
        else { acc.x += v2.x; acc.y += v2.y; acc.z += v2.z; acc.w += v2.w; }

        int s3 = (__shfl(pack, p + 3) >> sh) & 0xFFFF;
        if (s3 != cur_seg) { flush_acc(out, cur_seg, cq, acc); cur_seg = s3; acc = v3; }
        else { acc.x += v3.x; acc.y += v3.y; acc.z += v3.z; acc.w += v3.w; }
    }
    // Remainder pairs.
    for (; p < npairs; ++p, xp += 2 * D4) {
        float4 v = xp[0];
        int s = (__shfl(pack, p) >> sh) & 0xFFFF;
        if (s != cur_seg) { flush_acc(out, cur_seg, cq, acc); cur_seg = s; acc = v; }
        else { acc.x += v.x; acc.y += v.y; acc.z += v.z; acc.w += v.w; }
    }
    // Odd last row: processed by half 0 only (shuffle outside the branch).
    if (odd) {
        int s = (__shfl(pack, npairs) >> sh) & 0xFFFF;
        if (half == 0) {
            float4 v = ((const float4*)x)[(rend - 1) * (long)D4 + cq];
            if (s != cur_seg) { flush_acc(out, cur_seg, cq, acc); cur_seg = s; acc = v; }
            else { acc.x += v.x; acc.y += v.y; acc.z += v.z; acc.w += v.w; }
        }
    }

    flush_acc(out, cur_seg, cq, acc);
}

extern "C" void kernel_launch(void* const* d_in, const int* in_sizes, int n_in,
                              void* d_out, int out_size, void* d_ws, size_t ws_size,
                              hipStream_t stream) {
    const float* x = (const float*)d_in[0];
    const int* index = (const int*)d_in[1];
    float* out = (float*)d_out;

    const int n_rows = in_sizes[1];           // 1,000,000
    const int n_out4 = out_size / 4;          // out_size = 16384*128

    // Zero the (poisoned) output first.
    zero_out_kernel<<<256, 256, 0, stream>>>((float4*)out, n_out4);

    const long n_waves = ((long)n_rows + ROWS_PER_WAVE - 1) / ROWS_PER_WAVE;
    const int n_blocks = (int)((n_waves + WAVES_PER_BLOCK - 1) / WAVES_PER_BLOCK);
    segsum_kernel<<<n_blocks, 256, 0, stream>>>(x, index, out, n_rows);
}

// Round 3
// 656.406 us; speedup vs baseline: 1.0224x; 1.0224x over previous
//
#include <hip/hip_runtime.h>

// SumPooling / segment_sum: out[s, d] = sum_{i: index[i]==s} x[i, d]
// x: (1e6, 128) fp32, index: (1e6,) sorted int32, out: (16384, 128) fp32.
//
// v4 strategy: SEGMENT OWNERSHIP — one 64-lane wave per output segment.
//  - index is sorted => segment s is the contiguous row range
//    [lower_bound(s), lower_bound(s+1)). Each wave binary-searches its two
//    bounds (20 probes, index is 4MB => L2-resident) and then streams its
//    rows with UNCONDITIONAL float4 loads: no per-row branches, no shfls,
//    no atomics anywhere.
//  - lanes 0-31 take even rows, lanes 32-63 odd rows: each load instruction
//    covers 2 full rows = 1 KiB contiguous; 4 loads in flight per wave.
//  - epilogue: cross-half shuffle reduce, lanes 0-31 store one float4 =>
//    512 B coalesced store per wave. Every segment (incl. empty ones) is
//    written exactly once => poisoned output fully overwritten, NO zero
//    kernel and NO atomicAdd. Single dispatch total.

constexpr int D_FEAT = 128;
constexpr int D4 = D_FEAT / 4;           // float4 per row = 32
constexpr int WAVES_PER_BLOCK = 4;       // block = 256 threads

__global__ __launch_bounds__(256, 8) void segsum_by_segment(
        const float* __restrict__ x,
        const int* __restrict__ index,
        float* __restrict__ out,
        int n_rows, int n_segments) {
    const int lane = threadIdx.x & 63;
    const int half = lane >> 5;          // 0: even rows, 1: odd rows
    const int cq   = lane & 31;          // float4 column within the row
    const int seg  = blockIdx.x * WAVES_PER_BLOCK + (threadIdx.x >> 6);
    if (seg >= n_segments) return;

    // lower_bound(seg + (lane&1)): even lanes find start, odd lanes find end.
    // All lanes run the same ~20-step loop (uniform trip count, 2 distinct
    // probe addresses per step -> broadcast-friendly L2 hits).
    int target = seg + (lane & 1);
    int lo = 0, hi = n_rows;
    while (lo < hi) {
        int mid = (lo + hi) >> 1;
        if (index[mid] < target) lo = mid + 1; else hi = mid;
    }
    const int start = __shfl(lo, 0);
    const int end   = __shfl(lo, 1);

    const int nr     = end - start;
    const int npairs = nr >> 1;

    float4 acc = make_float4(0.f, 0.f, 0.f, 0.f);

    // This lane's float4 pointer in row (start + half); advances 2 rows/pair.
    const float4* __restrict__ xp =
        (const float4*)x + (long)(start + half) * D4 + cq;

    int p = 0;
    // 4 pairs per batch = 8 rows, 4 independent loads in flight,
    // address = one base + imm offsets 0/1024/2048/3072 B.
    for (; p + 4 <= npairs; p += 4, xp += 8 * D4) {
        float4 v0 = xp[0 * 2 * D4];
        float4 v1 = xp[1 * 2 * D4];
        float4 v2 = xp[2 * 2 * D4];
        float4 v3 = xp[3 * 2 * D4];
        acc.x += v0.x; acc.y += v0.y; acc.z += v0.z; acc.w += v0.w;
        acc.x += v1.x; acc.y += v1.y; acc.z += v1.z; acc.w += v1.w;
        acc.x += v2.x; acc.y += v2.y; acc.z += v2.z; acc.w += v2.w;
        acc.x += v3.x; acc.y += v3.y; acc.z += v3.z; acc.w += v3.w;
    }
    for (; p < npairs; ++p, xp += 2 * D4) {
        float4 v = xp[0];
        acc.x += v.x; acc.y += v.y; acc.z += v.z; acc.w += v.w;
    }
    // Odd row count: last row handled by half 0 only.
    if ((nr & 1) && half == 0) {
        float4 v = ((const float4*)x)[(long)(end - 1) * D4 + cq];
        acc.x += v.x; acc.y += v.y; acc.z += v.z; acc.w += v.w;
    }

    // Cross-half reduction: lane i (+) lane i^32 hold the two row-parity
    // partial sums of the same column group.
    acc.x += __shfl(acc.x, lane ^ 32);
    acc.y += __shfl(acc.y, lane ^ 32);
    acc.z += __shfl(acc.z, lane ^ 32);
    acc.w += __shfl(acc.w, lane ^ 32);

    if (half == 0) {
        ((float4*)out)[(long)seg * D4 + cq] = acc;   // plain store, no atomic
    }
}

extern "C" void kernel_launch(void* const* d_in, const int* in_sizes, int n_in,
                              void* d_out, int out_size, void* d_ws, size_t ws_size,
                              hipStream_t stream) {
    const float* x = (const float*)d_in[0];
    const int* index = (const int*)d_in[1];
    float* out = (float*)d_out;

    const int n_rows = in_sizes[1];              // 1,000,000
    const int n_segments = out_size / D_FEAT;    // out_size in elements => 16384

    const int n_blocks = (n_segments + WAVES_PER_BLOCK - 1) / WAVES_PER_BLOCK;
    segsum_by_segment<<<n_blocks, 256, 0, stream>>>(x, index, out,
                                                    n_rows, n_segments);
}